// Round 3
// baseline (431.738 us; speedup 1.0000x reference)
//
#include <hip/hip_runtime.h>
#include <stdint.h>

#define B_ 64
#define T_ 2048
#define O_ 3
#define D_ 512
#define M_ 100000
#define H_ 4
#define HD_ 128
#define TC_ 128
#define NCH_ (T_ / TC_)
#define PSTR_ 132   // partials stride: [A 0..127][M @128][S @129], 16B-aligned

// primes[h][i]: x0 = 131 + h*1009; x_{k+1} = x_k*31 + 1 (no uint32 wrap occurs)
__device__ __constant__ unsigned PRIMES_c[H_][4] = {
  {131u,  4062u,  125923u, 3903614u},
  {1140u, 35341u, 1095572u, 33962733u},
  {2149u, 66620u, 2065221u, 64021852u},
  {3158u, 97899u, 3034870u, 94080971u},
};

template<int CTRL, int RMASK>
__device__ __forceinline__ float dpp_term(float x) {
  return __int_as_float(__builtin_amdgcn_update_dpp(
      0, __float_as_int(x), CTRL, RMASK, 0xF, true));
}

// 32-lane sum, independently in each wave half, broadcast within the half.
__device__ __forceinline__ float red32(float x) {
  x += dpp_term<0xB1, 0xF>(x);   // xor 1 (quad_perm [1,0,3,2])
  x += dpp_term<0x4E, 0xF>(x);   // xor 2 (quad_perm [2,3,0,1])
  x += dpp_term<0x141, 0xF>(x);  // xor 4 (row_half_mirror)
  x += dpp_term<0x140, 0xF>(x);  // xor 8 (row_mirror)
  x += __shfl_xor(x, 16, 64);    // xor 16 -> 32-lane sum in all 32 lanes
  return x;
}

// Full 64-lane sum, broadcast to all lanes (epilogue only).
__device__ __forceinline__ float wave_sum(float x) {
  x += dpp_term<0xB1, 0xF>(x);
  x += dpp_term<0x4E, 0xF>(x);
  x += dpp_term<0x141, 0xF>(x);
  x += dpp_term<0x140, 0xF>(x);
  x += dpp_term<0x142, 0xA>(x);  // row_bcast:15 -> rows 1,3
  x += dpp_term<0x143, 0xC>(x);  // row_bcast:31 -> rows 2,3 ; lane63 = total
  return __int_as_float(__builtin_amdgcn_readlane(__float_as_int(x), 63));
}

__device__ __forceinline__ bool read_mask(const void* mb, size_t i, int imode) {
  return imode ? (((const int*)mb)[i] != 0)
               : (((const unsigned char*)mb)[i] != 0);
}

// Per-block mask dtype detection: wave 0 scans first 2048 words (8 KB, valid
// in both modes). int32 mode => every word is 0/1; packed bools exceed 1 with
// prob 1-8^-2048.
__device__ __forceinline__ void detect_imode(const void* maskbuf, int tid,
                                             int* s_imode) {
  if (tid < 64) {
    const uint4* mw = (const uint4*)maskbuf;
    unsigned bad = 0;
    #pragma unroll
    for (int i = 0; i < 8; ++i) {
      uint4 v = mw[tid + i * 64];
      bad |= (v.x > 1u) | (v.y > 1u) | (v.z > 1u) | (v.w > 1u);
    }
    unsigned long long anybad = __ballot(bad != 0);
    if (tid == 0) *s_imode = (anybad == 0ull) ? 1 : 0;
  }
}

__global__ __launch_bounds__(256) void k_fused(
    const int* __restrict__ tokens, const int* __restrict__ prev,
    const void* __restrict__ maskbuf, const float* __restrict__ embed,
    const float* __restrict__ engram, const float* __restrict__ gate_logit,
    const float* __restrict__ temp, const float* __restrict__ salW,
    const float* __restrict__ salb, const float* __restrict__ gateW,
    const float* __restrict__ gateb, const float* __restrict__ rms_scale,
    int* __restrict__ cnt, float* __restrict__ partials,
    float* __restrict__ out)
{
  int blk = blockIdx.x;
  int b = blk / NCH_, c = blk % NCH_;
  int t0 = c * TC_;
  int tid = threadIdx.x;
  int h = tid >> 6, lane = tid & 63;
  int half = lane >> 5, sl = lane & 31;

  __shared__ int s_imode;
  __shared__ int ltok[TC_ + 3];
  __shared__ unsigned eoff[TC_ * H_];
  __shared__ int s_act[TC_];
  __shared__ int s_cnt2[2];
  __shared__ int s_nact;
  __shared__ int s_last;
  __shared__ float s_ss[H_];

  detect_imode(maskbuf, tid, &s_imode);
  for (int j = tid; j < TC_ + 3; j += 256) {
    int g = t0 + j;
    ltok[j] = (g < O_) ? prev[b * O_ + g] : tokens[(size_t)b * T_ + g - O_];
  }
  __syncthreads();

  int imode = s_imode;
  // ballot compaction of active timesteps (threads 0..127 cover j=tid)
  bool act = false;
  unsigned long long bal = 0;
  if (tid < TC_) {
    act = read_mask(maskbuf, (size_t)b * T_ + t0 + tid, imode);
    bal = __ballot(act);
    if ((tid & 63) == 0) s_cnt2[tid >> 6] = __popcll(bal);
  }
  __syncthreads();
  if (tid < TC_) {
    int l = tid & 63;
    int pre = __popcll(bal & ((1ull << l) - 1));
    int base = (tid >> 6) ? s_cnt2[0] : 0;
    if (act) s_act[base + pre] = tid;
    if (tid == 0) s_nact = s_cnt2[0] + s_cnt2[1];
  }
  __syncthreads();
  int nact = s_nact;

  // hash only for active timesteps: eoff[a*H + h]
  for (int k = tid; k < nact * H_; k += 256) {
    int a  = k >> 2;
    int hh = k & 3;
    int j  = s_act[a];
    unsigned hs = (unsigned)ltok[j + 3] * PRIMES_c[hh][0]
                + (unsigned)ltok[j + 2] * PRIMES_c[hh][1]
                + (unsigned)ltok[j + 1] * PRIMES_c[hh][2]
                + (unsigned)ltok[j]     * PRIMES_c[hh][3];
    unsigned idx = hs % (unsigned)M_;
    eoff[k] = idx * (unsigned)(H_ * HD_) + (unsigned)(hh * HD_);
  }
  __syncthreads();

  // ---- main loop: half-wave split, 2 timesteps per wave trip ----
  int d0 = sl * 4;
  int gd = h * HD_ + d0;
  float4 glv = *(const float4*)(gate_logit + gd);
  float g0 = 1.f / (1.f + __expf(-glv.x));
  float g1 = 1.f / (1.f + __expf(-glv.y));
  float g2 = 1.f / (1.f + __expf(-glv.z));
  float g3 = 1.f / (1.f + __expf(-glv.w));
  float w0 = salW[(gd + 0) * H_ + h];
  float w1 = salW[(gd + 1) * H_ + h];
  float w2 = salW[(gd + 2) * H_ + h];
  float w3 = salW[(gd + 3) * H_ + h];
  float tv = temp[h];
  float sp = (tv > 20.f) ? tv : log1pf(__expf(tv));
  float invT = 1.f / (sp + 0.3f);
  float sb = salb[h];

  float m = -1e30f, s = 0.f;
  float a0 = 0.f, a1 = 0.f, a2 = 0.f, a3 = 0.f;

  #pragma unroll 2
  for (int k = 0; k < nact; k += 2) {
    int ka = k + half;
    bool valid = ka < nact;
    int aidx = valid ? ka : (nact - 1);   // clamp; dummy zeroed via exp
    int j = s_act[aidx];
    int tokc = ltok[j + 3];
    unsigned eo = eoff[aidx * H_ + h];
    float4 r = *(const float4*)(engram + eo + d0);
    float4 e = *(const float4*)(embed + tokc * D_ + gd);
    float x0 = fmaf(r.x, g0, e.x);
    float x1 = fmaf(r.y, g1, e.y);
    float x2 = fmaf(r.z, g2, e.z);
    float x3 = fmaf(r.w, g3, e.w);
    float pd = fmaf(x3, w3, fmaf(x2, w2, fmaf(x1, w1, x0 * w0)));
    float dot = red32(pd);
    float logit = valid ? (dot + sb) * invT : -1e30f;
    float nm = fmaxf(m, logit);
    float al = __expf(m - nm);
    float w  = __expf(logit - nm);
    s  = fmaf(s,  al, w);
    a0 = fmaf(a0, al, w * x0);
    a1 = fmaf(a1, al, w * x1);
    a2 = fmaf(a2, al, w * x2);
    a3 = fmaf(a3, al, w * x3);
    m = nm;
  }
  // merge halves (dummy-tail half has m=-1e30 => factor exp(-1e30-M)=0)
  float pm = __shfl_xor(m, 32, 64);
  float M2 = fmaxf(m, pm);
  float fs = __expf(m - M2);
  float fp = __expf(pm - M2);
  float S2 = fmaf(s, fs, __shfl_xor(s, 32, 64) * fp);
  float A0 = fmaf(a0, fs, __shfl_xor(a0, 32, 64) * fp);
  float A1 = fmaf(a1, fs, __shfl_xor(a1, 32, 64) * fp);
  float A2 = fmaf(a2, fs, __shfl_xor(a2, 32, 64) * fp);
  float A3 = fmaf(a3, fs, __shfl_xor(a3, 32, 64) * fp);

  float* P = partials + ((size_t)(b * NCH_ + c) * H_ + h) * PSTR_;
  if (half == 0) {
    *(float4*)(P + d0) = make_float4(A0, A1, A2, A3);
    if (sl == 0) { P[HD_] = M2; P[HD_ + 1] = S2; }
  }

  // ---- last chunk-block for this b runs the epilogue ----
  __threadfence();       // release partials writes (agent scope: wbl2)
  __syncthreads();
  if (tid == 0) {
    int old = atomicAdd(&cnt[b], 1);
    s_last = (old == NCH_ - 1) ? 1 : 0;
  }
  __syncthreads();
  if (!s_last) return;
  __threadfence();       // acquire: invalidate stale cache before reads

  int d0f = lane * 2;
  const float* Pb = partials + (size_t)b * NCH_ * H_ * PSTR_;
  float M = -1e30f;
  for (int cc = 0; cc < NCH_; ++cc)
    M = fmaxf(M, Pb[(cc * H_ + h) * PSTR_ + HD_]);
  float S = 0.f, B0 = 0.f, B1 = 0.f;
  for (int cc = 0; cc < NCH_; ++cc) {
    const float* Pc = Pb + (cc * H_ + h) * PSTR_;
    float f = __expf(Pc[HD_] - M);
    float2 a = *(const float2*)(Pc + d0f);
    S  = fmaf(Pc[HD_ + 1], f, S);
    B0 = fmaf(a.x, f, B0);
    B1 = fmaf(a.y, f, B1);
  }
  float inv = 1.f / (S + 1e-6f);
  float v0 = B0 * inv, v1 = B1 * inv;   // write_vec_heads[b][h][d0f, d0f+1]

  float pg = v0 * gateW[d0f] + v1 * gateW[d0f + 1];
  float ss = v0 * v0 + v1 * v1;
  float gl  = wave_sum(pg);
  float sst = wave_sum(ss);
  if (lane == 0) s_ss[h] = sst;
  __syncthreads();
  float tot = s_ss[0] + s_ss[1] + s_ss[2] + s_ss[3];
  float rinv = rsqrtf(tot / (float)D_ + 1e-6f);
  // any(mask) <=> S >= 1 (global-max timestep contributes weight 1)
  float anyf = (S > 0.5f) ? 1.f : 0.f;
  float u = (1.f / (1.f + __expf(-(gl + gateb[0])))) * anyf;

  int gdf = h * HD_ + d0f;
  size_t ob = (size_t)b * (2 * D_);
  out[ob + gdf]          = v0 * rinv * rms_scale[gdf];
  out[ob + gdf + 1]      = v1 * rinv * rms_scale[gdf + 1];
  out[ob + D_ + gdf]     = u;
  out[ob + D_ + gdf + 1] = u;
}

extern "C" void kernel_launch(void* const* d_in, const int* in_sizes, int n_in,
                              void* d_out, int out_size, void* d_ws, size_t ws_size,
                              hipStream_t stream)
{
  const int*   tokens     = (const int*)d_in[0];
  const int*   prev       = (const int*)d_in[1];
  const void*  mask       = d_in[2];
  const float* embed      = (const float*)d_in[3];
  const float* engram     = (const float*)d_in[4];
  const float* gate_logit = (const float*)d_in[5];
  const float* temp       = (const float*)d_in[6];
  const float* salW       = (const float*)d_in[7];
  const float* salb       = (const float*)d_in[8];
  const float* gateW      = (const float*)d_in[9];
  const float* gateb      = (const float*)d_in[10];
  const float* rms_scale  = (const float*)d_in[11];
  float* out = (float*)d_out;

  int*   cnt      = (int*)d_ws;                       // 64 counters
  float* partials = (float*)((char*)d_ws + 256);      // ~2.2 MB

  hipMemsetAsync(cnt, 0, 256, stream);                // ws is re-poisoned 0xAA
  k_fused<<<B_ * NCH_, 256, 0, stream>>>(
      tokens, prev, mask, embed, engram, gate_logit, temp, salW, salb,
      gateW, gateb, rms_scale, cnt, partials, out);
}

// Round 4
// 286.805 us; speedup vs baseline: 1.5053x; 1.5053x over previous
//
#include <hip/hip_runtime.h>
#include <stdint.h>

#define B_ 64
#define T_ 2048
#define O_ 3
#define D_ 512
#define M_ 100000
#define H_ 4
#define HD_ 128
#define TC_ 128
#define NCH_ (T_ / TC_)
#define PSTR_ 132   // partials: [A 0..127][m @128][s @129]; 528 B = 33*16, aligned

// primes[h][i]: x0 = 131 + h*1009; x_{k+1} = x_k*31 + 1 (no uint32 wrap occurs)
__device__ __constant__ unsigned PRIMES_c[H_][4] = {
  {131u,  4062u,  125923u, 3903614u},
  {1140u, 35341u, 1095572u, 33962733u},
  {2149u, 66620u, 2065221u, 64021852u},
  {3158u, 97899u, 3034870u, 94080971u},
};

template<int CTRL, int RMASK>
__device__ __forceinline__ float dpp_term(float x) {
  return __int_as_float(__builtin_amdgcn_update_dpp(
      0, __float_as_int(x), CTRL, RMASK, 0xF, true));
}

// 32-lane sum, independently in each wave half, broadcast within the half.
__device__ __forceinline__ float red32(float x) {
  x += dpp_term<0xB1, 0xF>(x);   // xor 1
  x += dpp_term<0x4E, 0xF>(x);   // xor 2
  x += dpp_term<0x141, 0xF>(x);  // xor 4
  x += dpp_term<0x140, 0xF>(x);  // xor 8
  x += __shfl_xor(x, 16, 64);    // xor 16
  return x;
}

// Full 64-lane sum broadcast (epilogue only).
__device__ __forceinline__ float wave_sum(float x) {
  x += dpp_term<0xB1, 0xF>(x);
  x += dpp_term<0x4E, 0xF>(x);
  x += dpp_term<0x141, 0xF>(x);
  x += dpp_term<0x140, 0xF>(x);
  x += dpp_term<0x142, 0xA>(x);  // row_bcast:15 -> rows 1,3
  x += dpp_term<0x143, 0xC>(x);  // row_bcast:31 -> rows 2,3
  return __int_as_float(__builtin_amdgcn_readlane(__float_as_int(x), 63));
}

__device__ __forceinline__ bool read_mask(const void* mb, size_t i, int imode) {
  return imode ? (((const int*)mb)[i] != 0)
               : (((const unsigned char*)mb)[i] != 0);
}

// Per-block mask dtype detection: wave 0 scans first 2048 words (8 KB, valid
// in both modes). int32 mode => every word is 0/1.
__device__ __forceinline__ void detect_imode(const void* maskbuf, int tid,
                                             int* s_imode) {
  if (tid < 64) {
    const uint4* mw = (const uint4*)maskbuf;
    unsigned bad = 0;
    #pragma unroll
    for (int i = 0; i < 8; ++i) {
      uint4 v = mw[tid + i * 64];
      bad |= (v.x > 1u) | (v.y > 1u) | (v.z > 1u) | (v.w > 1u);
    }
    unsigned long long anybad = __ballot(bad != 0);
    if (tid == 0) *s_imode = (anybad == 0ull) ? 1 : 0;
  }
}

__global__ __launch_bounds__(256) void k_pass1(
    const int* __restrict__ tokens, const int* __restrict__ prev,
    const void* __restrict__ maskbuf, const float* __restrict__ embed,
    const float* __restrict__ engram, const float* __restrict__ gate_logit,
    const float* __restrict__ temp, const float* __restrict__ salW,
    const float* __restrict__ salb, float* __restrict__ partials)
{
  int blk = blockIdx.x;
  int b = blk / NCH_, c = blk % NCH_;
  int t0 = c * TC_;
  int tid = threadIdx.x;
  int h = tid >> 6, lane = tid & 63;
  int half = lane >> 5, sl = lane & 31;

  __shared__ int s_imode;
  __shared__ int ltok[TC_ + 3];
  __shared__ unsigned eoff[TC_ * H_];
  __shared__ int s_act[TC_];
  __shared__ int s_cnt2[2];
  __shared__ int s_nact;

  detect_imode(maskbuf, tid, &s_imode);
  for (int j = tid; j < TC_ + 3; j += 256) {
    int g = t0 + j;
    ltok[j] = (g < O_) ? prev[b * O_ + g] : tokens[(size_t)b * T_ + g - O_];
  }
  __syncthreads();

  int imode = s_imode;
  // ballot compaction of active timesteps (threads 0..127 cover j=tid)
  bool act = false;
  unsigned long long bal = 0;
  if (tid < TC_) {
    act = read_mask(maskbuf, (size_t)b * T_ + t0 + tid, imode);
    bal = __ballot(act);
    if ((tid & 63) == 0) s_cnt2[tid >> 6] = __popcll(bal);
  }
  __syncthreads();
  if (tid < TC_) {
    int l = tid & 63;
    int pre = __popcll(bal & ((1ull << l) - 1));
    int base = (tid >> 6) ? s_cnt2[0] : 0;
    if (act) s_act[base + pre] = tid;
    if (tid == 0) s_nact = s_cnt2[0] + s_cnt2[1];
  }
  __syncthreads();
  int nact = s_nact;

  // hash only for active timesteps: eoff[a*H + h]
  for (int k = tid; k < nact * H_; k += 256) {
    int a  = k >> 2;
    int hh = k & 3;
    int j  = s_act[a];
    unsigned hs = (unsigned)ltok[j + 3] * PRIMES_c[hh][0]
                + (unsigned)ltok[j + 2] * PRIMES_c[hh][1]
                + (unsigned)ltok[j + 1] * PRIMES_c[hh][2]
                + (unsigned)ltok[j]     * PRIMES_c[hh][3];
    unsigned idx = hs % (unsigned)M_;
    eoff[k] = idx * (unsigned)(H_ * HD_) + (unsigned)(hh * HD_);
  }
  __syncthreads();

  // ---- main loop: half-wave split, 2 t per half per trip (4 t/wave) ----
  int d0 = sl * 4;
  int gd = h * HD_ + d0;
  float4 glv = *(const float4*)(gate_logit + gd);
  float g0 = 1.f / (1.f + __expf(-glv.x));
  float g1 = 1.f / (1.f + __expf(-glv.y));
  float g2 = 1.f / (1.f + __expf(-glv.z));
  float g3 = 1.f / (1.f + __expf(-glv.w));
  float w0 = salW[(gd + 0) * H_ + h];
  float w1 = salW[(gd + 1) * H_ + h];
  float w2 = salW[(gd + 2) * H_ + h];
  float w3 = salW[(gd + 3) * H_ + h];
  float tv = temp[h];
  float sp = (tv > 20.f) ? tv : log1pf(__expf(tv));
  float invT = 1.f / (sp + 0.3f);
  float sb = salb[h];

  float m = -1e30f, s = 0.f;
  float a0 = 0.f, a1 = 0.f, a2 = 0.f, a3 = 0.f;

  for (int k = 0; k < nact; k += 4) {
    int ka = k + half, kb = k + 2 + half;
    bool va = ka < nact, vb = kb < nact;
    int ia = va ? ka : 0;
    int ib = vb ? kb : 0;
    int ja = s_act[ia], jb = s_act[ib];
    unsigned eoa = eoff[ia * H_ + h], eob = eoff[ib * H_ + h];
    int ta = ltok[ja + 3], tb = ltok[jb + 3];
    float4 ra = *(const float4*)(engram + eoa + d0);
    float4 rb = *(const float4*)(engram + eob + d0);
    float4 ea = *(const float4*)(embed + ta * D_ + gd);
    float4 eb = *(const float4*)(embed + tb * D_ + gd);
    float xa0 = fmaf(ra.x, g0, ea.x);
    float xa1 = fmaf(ra.y, g1, ea.y);
    float xa2 = fmaf(ra.z, g2, ea.z);
    float xa3 = fmaf(ra.w, g3, ea.w);
    float xb0 = fmaf(rb.x, g0, eb.x);
    float xb1 = fmaf(rb.y, g1, eb.y);
    float xb2 = fmaf(rb.z, g2, eb.z);
    float xb3 = fmaf(rb.w, g3, eb.w);
    float pda = fmaf(xa3, w3, fmaf(xa2, w2, fmaf(xa1, w1, xa0 * w0)));
    float pdb = fmaf(xb3, w3, fmaf(xb2, w2, fmaf(xb1, w1, xb0 * w0)));
    float da = red32(pda);
    float db = red32(pdb);
    float la = va ? (da + sb) * invT : -1e30f;
    float lb = vb ? (db + sb) * invT : -1e30f;
    // batched online-softmax update (3 independent exps)
    float nm = fmaxf(m, fmaxf(la, lb));
    float al = __expf(m - nm);
    float wa = __expf(la - nm);
    float wb = __expf(lb - nm);
    s  = fmaf(s,  al, wa + wb);
    a0 = fmaf(a0, al, fmaf(wa, xa0, wb * xb0));
    a1 = fmaf(a1, al, fmaf(wa, xa1, wb * xb1));
    a2 = fmaf(a2, al, fmaf(wa, xa2, wb * xb2));
    a3 = fmaf(a3, al, fmaf(wa, xa3, wb * xb3));
    m = nm;
    // note: if this half's batch is all-invalid, m stays -1e30 and any
    // contamination (exp(0)=1) is zeroed by the half-merge factor below.
  }

  // merge halves (dummy half has m=-1e30 => factor exp(-1e30 - M2) = 0)
  float pm = __shfl_xor(m, 32, 64);
  float M2 = fmaxf(m, pm);
  float fs = __expf(m - M2);
  float fp = __expf(pm - M2);
  float S2 = fmaf(s, fs, __shfl_xor(s, 32, 64) * fp);
  float A0 = fmaf(a0, fs, __shfl_xor(a0, 32, 64) * fp);
  float A1 = fmaf(a1, fs, __shfl_xor(a1, 32, 64) * fp);
  float A2 = fmaf(a2, fs, __shfl_xor(a2, 32, 64) * fp);
  float A3 = fmaf(a3, fs, __shfl_xor(a3, 32, 64) * fp);

  float* P = partials + ((size_t)(b * NCH_ + c) * H_ + h) * PSTR_;
  if (half == 0) {
    *(float4*)(P + d0) = make_float4(A0, A1, A2, A3);
    if (sl == 0) { P[HD_] = M2; P[HD_ + 1] = S2; }
  }
}

__global__ __launch_bounds__(256) void k_pass2(
    const float* __restrict__ partials, const void* __restrict__ maskbuf,
    const float* __restrict__ gateW, const float* __restrict__ gateb,
    const float* __restrict__ rms_scale, float* __restrict__ out)
{
  int b = blockIdx.x;
  int tid = threadIdx.x, h = tid >> 6, lane = tid & 63;

  __shared__ int s_imode;
  __shared__ float s_ss[H_];
  detect_imode(maskbuf, tid, &s_imode);
  __syncthreads();

  int d0 = lane * 2;
  const float* Pb = partials + (size_t)b * NCH_ * H_ * PSTR_;
  float M = -1e30f;
  for (int cc = 0; cc < NCH_; ++cc)
    M = fmaxf(M, Pb[(cc * H_ + h) * PSTR_ + HD_]);
  float S = 0.f, B0 = 0.f, B1 = 0.f;
  for (int cc = 0; cc < NCH_; ++cc) {
    const float* Pc = Pb + (cc * H_ + h) * PSTR_;
    float f = __expf(Pc[HD_] - M);
    float2 a = *(const float2*)(Pc + d0);
    S  = fmaf(Pc[HD_ + 1], f, S);
    B0 = fmaf(a.x, f, B0);
    B1 = fmaf(a.y, f, B1);
  }
  float inv = 1.f / (S + 1e-6f);
  float v0 = B0 * inv, v1 = B1 * inv;   // write_vec_heads[b][h][d0, d0+1]

  float pg = v0 * gateW[d0] + v1 * gateW[d0 + 1];
  float ss = v0 * v0 + v1 * v1;
  float gl  = wave_sum(pg);
  float sst = wave_sum(ss);
  if (lane == 0) s_ss[h] = sst;
  __syncthreads();
  float tot = s_ss[0] + s_ss[1] + s_ss[2] + s_ss[3];
  float rinv = rsqrtf(tot / (float)D_ + 1e-6f);
  // any(mask) <=> S >= 1 (global-max timestep contributes weight exactly 1)
  float anyf = (S > 0.5f) ? 1.f : 0.f;
  float u = (1.f / (1.f + __expf(-(gl + gateb[0])))) * anyf;

  int gd = h * HD_ + d0;
  size_t ob = (size_t)b * (2 * D_);
  out[ob + gd]          = v0 * rinv * rms_scale[gd];
  out[ob + gd + 1]      = v1 * rinv * rms_scale[gd + 1];
  out[ob + D_ + gd]     = u;
  out[ob + D_ + gd + 1] = u;
}

extern "C" void kernel_launch(void* const* d_in, const int* in_sizes, int n_in,
                              void* d_out, int out_size, void* d_ws, size_t ws_size,
                              hipStream_t stream)
{
  const int*   tokens     = (const int*)d_in[0];
  const int*   prev       = (const int*)d_in[1];
  const void*  mask       = d_in[2];
  const float* embed      = (const float*)d_in[3];
  const float* engram     = (const float*)d_in[4];
  const float* gate_logit = (const float*)d_in[5];
  const float* temp       = (const float*)d_in[6];
  const float* salW       = (const float*)d_in[7];
  const float* salb       = (const float*)d_in[8];
  const float* gateW      = (const float*)d_in[9];
  const float* gateb      = (const float*)d_in[10];
  const float* rms_scale  = (const float*)d_in[11];
  float* out = (float*)d_out;

  float* partials = (float*)d_ws;

  k_pass1<<<B_ * NCH_, 256, 0, stream>>>(
      tokens, prev, mask, embed, engram, gate_logit, temp, salW, salb,
      partials);
  k_pass2<<<B_, 256, 0, stream>>>(
      partials, mask, gateW, gateb, rms_scale, out);
}

// Round 5
// 284.191 us; speedup vs baseline: 1.5192x; 1.0092x over previous
//
#include <hip/hip_runtime.h>
#include <stdint.h>

#define B_ 64
#define T_ 2048
#define O_ 3
#define D_ 512
#define M_ 100000
#define H_ 4
#define HD_ 128
#define TC_ 64
#define NCH_ (T_ / TC_)   // 32
#define PSTR_ 132   // partials: [A 0..127][m @128][s @129]; 528 B, 16B-aligned

// primes[h][i]: x0 = 131 + h*1009; x_{k+1} = x_k*31 + 1 (no uint32 wrap occurs)
__device__ __constant__ unsigned PRIMES_c[H_][4] = {
  {131u,  4062u,  125923u, 3903614u},
  {1140u, 35341u, 1095572u, 33962733u},
  {2149u, 66620u, 2065221u, 64021852u},
  {3158u, 97899u, 3034870u, 94080971u},
};

template<int CTRL, int RMASK>
__device__ __forceinline__ float dpp_term(float x) {
  return __int_as_float(__builtin_amdgcn_update_dpp(
      0, __float_as_int(x), CTRL, RMASK, 0xF, true));
}

// 32-lane sum, independently in each wave half, broadcast within the half.
__device__ __forceinline__ float red32(float x) {
  x += dpp_term<0xB1, 0xF>(x);   // xor 1
  x += dpp_term<0x4E, 0xF>(x);   // xor 2
  x += dpp_term<0x141, 0xF>(x);  // xor 4
  x += dpp_term<0x140, 0xF>(x);  // xor 8
  x += __shfl_xor(x, 16, 64);    // xor 16
  return x;
}

// Full 64-lane sum broadcast (epilogue only).
__device__ __forceinline__ float wave_sum(float x) {
  x += dpp_term<0xB1, 0xF>(x);
  x += dpp_term<0x4E, 0xF>(x);
  x += dpp_term<0x141, 0xF>(x);
  x += dpp_term<0x140, 0xF>(x);
  x += dpp_term<0x142, 0xA>(x);  // row_bcast:15 -> rows 1,3
  x += dpp_term<0x143, 0xC>(x);  // row_bcast:31 -> rows 2,3
  return __int_as_float(__builtin_amdgcn_readlane(__float_as_int(x), 63));
}

// Per-block mask dtype detection: wave 0 scans first 2048 words (8 KB, valid
// in both modes). int32 mode => every word is 0/1.
__device__ __forceinline__ void detect_imode(const void* maskbuf, int tid,
                                             int* s_imode) {
  if (tid < 64) {
    const uint4* mw = (const uint4*)maskbuf;
    unsigned bad = 0;
    #pragma unroll
    for (int i = 0; i < 8; ++i) {
      uint4 v = mw[tid + i * 64];
      bad |= (v.x > 1u) | (v.y > 1u) | (v.z > 1u) | (v.w > 1u);
    }
    unsigned long long anybad = __ballot(bad != 0);
    if (tid == 0) *s_imode = (anybad == 0ull) ? 1 : 0;
  }
}

__global__ __launch_bounds__(256) void k_pass1(
    const int* __restrict__ tokens, const int* __restrict__ prev,
    const void* __restrict__ maskbuf, const float* __restrict__ embed,
    const float* __restrict__ engram, const float* __restrict__ gate_logit,
    const float* __restrict__ temp, const float* __restrict__ salW,
    const float* __restrict__ salb, float* __restrict__ partials)
{
  int blk = blockIdx.x;
  int b = blk / NCH_, c = blk % NCH_;
  int t0 = c * TC_;
  int tid = threadIdx.x;
  int h = tid >> 6, lane = tid & 63;
  int half = lane >> 5, sl = lane & 31;

  __shared__ int s_imode;
  __shared__ int ltok[TC_ + 3];
  __shared__ unsigned eoff[TC_ * H_];   // engram float-offset per (act, h)
  __shared__ int ltokc[TC_];            // compacted current-token per act idx
  __shared__ int s_act[TC_];
  __shared__ int s_nact;

  detect_imode(maskbuf, tid, &s_imode);
  if (tid < TC_ + 3) {
    int g = t0 + tid;
    ltok[tid] = (g < O_) ? prev[b * O_ + g] : tokens[(size_t)b * T_ + g - O_];
  }
  // speculative dual-mode mask read (issues in parallel with detect loads)
  bool act_i = false, act_b = false;
  if (tid < TC_) {
    size_t mi = (size_t)b * T_ + t0 + tid;
    act_i = ((const int*)maskbuf)[mi] != 0;
    act_b = ((const unsigned char*)maskbuf)[mi] != 0;
  }
  __syncthreads();

  // ballot compaction of active timesteps (wave 0 covers j = tid, TC_ == 64)
  if (tid < 64) {
    bool act = s_imode ? act_i : act_b;
    unsigned long long bal = __ballot(act);
    int pre = __popcll(bal & ((1ull << tid) - 1));
    if (act) s_act[pre] = tid;
    if (tid == 0) s_nact = __popcll(bal);
  }
  __syncthreads();
  int nact = s_nact;

  // hash for active timesteps: eoff[a*H + h]; also compact current token
  if (tid < nact * H_) {
    int a  = tid >> 2;
    int hh = tid & 3;
    int j  = s_act[a];
    unsigned hs = (unsigned)ltok[j + 3] * PRIMES_c[hh][0]
                + (unsigned)ltok[j + 2] * PRIMES_c[hh][1]
                + (unsigned)ltok[j + 1] * PRIMES_c[hh][2]
                + (unsigned)ltok[j]     * PRIMES_c[hh][3];
    unsigned idx = hs % (unsigned)M_;
    eoff[tid] = idx * (unsigned)(H_ * HD_) + (unsigned)(hh * HD_);
    if (hh == 0) ltokc[a] = ltok[j + 3];
  }
  __syncthreads();

  // ---- main loop: half-wave split, 4 t per half per trip (8 t/wave) ----
  int d0 = sl * 4;
  int gd = h * HD_ + d0;
  float4 glv = *(const float4*)(gate_logit + gd);
  float g0 = 1.f / (1.f + __expf(-glv.x));
  float g1 = 1.f / (1.f + __expf(-glv.y));
  float g2 = 1.f / (1.f + __expf(-glv.z));
  float g3 = 1.f / (1.f + __expf(-glv.w));
  float w0 = salW[(gd + 0) * H_ + h];
  float w1 = salW[(gd + 1) * H_ + h];
  float w2 = salW[(gd + 2) * H_ + h];
  float w3 = salW[(gd + 3) * H_ + h];
  float tv = temp[h];
  float sp = (tv > 20.f) ? tv : log1pf(__expf(tv));
  float invT = 1.f / (sp + 0.3f);
  float sb = salb[h];

  float m = -1e30f, s = 0.f;
  float4 acc = make_float4(0.f, 0.f, 0.f, 0.f);

  for (int k = 0; k < nact; k += 8) {
    int bse = k + half * 4;
    bool v0 = bse + 0 < nact;
    bool v1 = bse + 1 < nact;
    bool v2 = bse + 2 < nact;
    bool v3 = bse + 3 < nact;
    int j0 = v0 ? bse + 0 : 0;
    int j1 = v1 ? bse + 1 : 0;
    int j2 = v2 ? bse + 2 : 0;
    int j3 = v3 ? bse + 3 : 0;
    unsigned e0 = eoff[j0 * H_ + h];
    unsigned e1 = eoff[j1 * H_ + h];
    unsigned e2 = eoff[j2 * H_ + h];
    unsigned e3 = eoff[j3 * H_ + h];
    int c0 = ltokc[j0], c1 = ltokc[j1], c2 = ltokc[j2], c3 = ltokc[j3];
    float4 r0 = *(const float4*)(engram + e0 + d0);
    float4 r1 = *(const float4*)(engram + e1 + d0);
    float4 r2 = *(const float4*)(engram + e2 + d0);
    float4 r3 = *(const float4*)(engram + e3 + d0);
    float4 q0 = *(const float4*)(embed + c0 * D_ + gd);
    float4 q1 = *(const float4*)(embed + c1 * D_ + gd);
    float4 q2 = *(const float4*)(embed + c2 * D_ + gd);
    float4 q3 = *(const float4*)(embed + c3 * D_ + gd);
    float4 x0v, x1v, x2v, x3v;
    x0v.x = fmaf(r0.x, g0, q0.x); x0v.y = fmaf(r0.y, g1, q0.y);
    x0v.z = fmaf(r0.z, g2, q0.z); x0v.w = fmaf(r0.w, g3, q0.w);
    x1v.x = fmaf(r1.x, g0, q1.x); x1v.y = fmaf(r1.y, g1, q1.y);
    x1v.z = fmaf(r1.z, g2, q1.z); x1v.w = fmaf(r1.w, g3, q1.w);
    x2v.x = fmaf(r2.x, g0, q2.x); x2v.y = fmaf(r2.y, g1, q2.y);
    x2v.z = fmaf(r2.z, g2, q2.z); x2v.w = fmaf(r2.w, g3, q2.w);
    x3v.x = fmaf(r3.x, g0, q3.x); x3v.y = fmaf(r3.y, g1, q3.y);
    x3v.z = fmaf(r3.z, g2, q3.z); x3v.w = fmaf(r3.w, g3, q3.w);
    float pd0 = fmaf(x0v.w, w3, fmaf(x0v.z, w2, fmaf(x0v.y, w1, x0v.x * w0)));
    float pd1 = fmaf(x1v.w, w3, fmaf(x1v.z, w2, fmaf(x1v.y, w1, x1v.x * w0)));
    float pd2 = fmaf(x2v.w, w3, fmaf(x2v.z, w2, fmaf(x2v.y, w1, x2v.x * w0)));
    float pd3 = fmaf(x3v.w, w3, fmaf(x3v.z, w2, fmaf(x3v.y, w1, x3v.x * w0)));
    float dt0 = red32(pd0);
    float dt1 = red32(pd1);
    float dt2 = red32(pd2);
    float dt3 = red32(pd3);
    float l0 = v0 ? (dt0 + sb) * invT : -1e30f;
    float l1 = v1 ? (dt1 + sb) * invT : -1e30f;
    float l2 = v2 ? (dt2 + sb) * invT : -1e30f;
    float l3 = v3 ? (dt3 + sb) * invT : -1e30f;
    float nm = fmaxf(fmaxf(fmaxf(l0, l1), fmaxf(l2, l3)), m);
    float al  = __expf(m  - nm);
    float u0 = __expf(l0 - nm);
    float u1 = __expf(l1 - nm);
    float u2 = __expf(l2 - nm);
    float u3 = __expf(l3 - nm);
    s = fmaf(s, al, (u0 + u1) + (u2 + u3));
    acc.x = fmaf(acc.x, al,
        fmaf(u3, x3v.x, fmaf(u2, x2v.x, fmaf(u1, x1v.x, u0 * x0v.x))));
    acc.y = fmaf(acc.y, al,
        fmaf(u3, x3v.y, fmaf(u2, x2v.y, fmaf(u1, x1v.y, u0 * x0v.y))));
    acc.z = fmaf(acc.z, al,
        fmaf(u3, x3v.z, fmaf(u2, x2v.z, fmaf(u1, x1v.z, u0 * x0v.z))));
    acc.w = fmaf(acc.w, al,
        fmaf(u3, x3v.w, fmaf(u2, x2v.w, fmaf(u1, x1v.w, u0 * x0v.w))));
    m = nm;
    // a half whose batch slots are all-invalid before any valid t keeps
    // m = -1e30; its contamination is zeroed by the merge factor below.
  }

  // merge halves (never-valid half has m = -1e30 => exp(-1e30 - M2) = 0)
  float pm = __shfl_xor(m, 32, 64);
  float M2 = fmaxf(m, pm);
  float fs = __expf(m - M2);
  float fp = __expf(pm - M2);
  float S2 = fmaf(s, fs, __shfl_xor(s, 32, 64) * fp);
  float A0 = fmaf(acc.x, fs, __shfl_xor(acc.x, 32, 64) * fp);
  float A1 = fmaf(acc.y, fs, __shfl_xor(acc.y, 32, 64) * fp);
  float A2 = fmaf(acc.z, fs, __shfl_xor(acc.z, 32, 64) * fp);
  float A3 = fmaf(acc.w, fs, __shfl_xor(acc.w, 32, 64) * fp);

  float* P = partials + ((size_t)(b * NCH_ + c) * H_ + h) * PSTR_;
  if (half == 0) {
    *(float4*)(P + d0) = make_float4(A0, A1, A2, A3);
    if (sl == 0) { P[HD_] = M2; P[HD_ + 1] = S2; }
  }
}

__global__ __launch_bounds__(256) void k_pass2(
    const float* __restrict__ partials, const float* __restrict__ gateW,
    const float* __restrict__ gateb, const float* __restrict__ rms_scale,
    float* __restrict__ out)
{
  int b = blockIdx.x;
  int tid = threadIdx.x, h = tid >> 6, lane = tid & 63;

  __shared__ float s_ss[H_];

  int d0 = lane * 2;
  const float* Pb = partials + (size_t)b * NCH_ * H_ * PSTR_;
  float M = -1e30f;
  for (int cc = 0; cc < NCH_; ++cc)
    M = fmaxf(M, Pb[(cc * H_ + h) * PSTR_ + HD_]);
  float S = 0.f, B0 = 0.f, B1 = 0.f;
  for (int cc = 0; cc < NCH_; ++cc) {
    const float* Pc = Pb + (cc * H_ + h) * PSTR_;
    float f = __expf(Pc[HD_] - M);
    float2 a = *(const float2*)(Pc + d0);
    S  = fmaf(Pc[HD_ + 1], f, S);
    B0 = fmaf(a.x, f, B0);
    B1 = fmaf(a.y, f, B1);
  }
  float inv = 1.f / (S + 1e-6f);
  float v0 = B0 * inv, v1 = B1 * inv;   // write_vec_heads[b][h][d0, d0+1]

  float pg = v0 * gateW[d0] + v1 * gateW[d0 + 1];
  float ss = v0 * v0 + v1 * v1;
  float gl  = wave_sum(pg);
  float sst = wave_sum(ss);
  if (lane == 0) s_ss[h] = sst;
  __syncthreads();
  float tot = s_ss[0] + s_ss[1] + s_ss[2] + s_ss[3];
  float rinv = rsqrtf(tot / (float)D_ + 1e-6f);
  // any(mask) <=> S >= 1 (global-max timestep contributes weight exactly 1)
  float anyf = (S > 0.5f) ? 1.f : 0.f;
  float u = (1.f / (1.f + __expf(-(gl + gateb[0])))) * anyf;

  int gd = h * HD_ + d0;
  size_t ob = (size_t)b * (2 * D_);
  out[ob + gd]          = v0 * rinv * rms_scale[gd];
  out[ob + gd + 1]      = v1 * rinv * rms_scale[gd + 1];
  out[ob + D_ + gd]     = u;
  out[ob + D_ + gd + 1] = u;
}

extern "C" void kernel_launch(void* const* d_in, const int* in_sizes, int n_in,
                              void* d_out, int out_size, void* d_ws, size_t ws_size,
                              hipStream_t stream)
{
  const int*   tokens     = (const int*)d_in[0];
  const int*   prev       = (const int*)d_in[1];
  const void*  mask       = d_in[2];
  const float* embed      = (const float*)d_in[3];
  const float* engram     = (const float*)d_in[4];
  const float* gate_logit = (const float*)d_in[5];
  const float* temp       = (const float*)d_in[6];
  const float* salW       = (const float*)d_in[7];
  const float* salb       = (const float*)d_in[8];
  const float* gateW      = (const float*)d_in[9];
  const float* gateb      = (const float*)d_in[10];
  const float* rms_scale  = (const float*)d_in[11];
  float* out = (float*)d_out;

  float* partials = (float*)d_ws;

  k_pass1<<<B_ * NCH_, 256, 0, stream>>>(
      tokens, prev, mask, embed, engram, gate_logit, temp, salW, salb,
      partials);
  k_pass2<<<B_, 256, 0, stream>>>(
      partials, gateW, gateb, rms_scale, out);
}